// Round 1
// baseline (493.226 us; speedup 1.0000x reference)
//
#include <hip/hip_runtime.h>

#define EPSF 1e-8f

constexpr int Bn = 64;    // batch
constexpr int Cc = 768;   // channels
constexpr int Nn = 1024;  // H*W
constexpr int Mm = 100;   // memory slots
constexpr int MP = 128;   // padded M
constexpr int PIX = 64;   // pixels per block

// Normalize memory rows and write transposed+padded: memT[c*MP + m], zero pad m>=100.
__global__ __launch_bounds__(256) void prep_memT(const float* __restrict__ mem,
                                                 float* __restrict__ memT) {
    int m = blockIdx.x;
    int tid = threadIdx.x;
    if (m >= Mm) {
        for (int c = tid; c < Cc; c += 256) memT[c * MP + m] = 0.f;
        return;
    }
    float ss = 0.f;
    for (int c = tid; c < Cc; c += 256) {
        float v = mem[m * Cc + c];
        ss += v * v;
    }
    __shared__ float red[256];
    red[tid] = ss;
    __syncthreads();
    for (int s = 128; s > 0; s >>= 1) {
        if (tid < s) red[tid] += red[tid + s];
        __syncthreads();
    }
    float inv = 1.f / fmaxf(sqrtf(red[0]), 1e-12f);
    for (int c = tid; c < Cc; c += 256) memT[c * MP + m] = mem[m * Cc + c] * inv;
}

__global__ __launch_bounds__(256) void fused_mem_kernel(
    const float* __restrict__ z, const float* __restrict__ mem,
    const float* __restrict__ memT, float* __restrict__ zhat,
    float* __restrict__ attn_out) {
    __shared__ float zs[32][64];    // 8 KB   z chunk
    __shared__ float ms[32][MP];    // 16 KB  memT chunk (reused as msC[20][128] in phase C)
    __shared__ float scr[PIX][MP];  // 32 KB  scores/e  (later aliased as attnT[m][px])
    __shared__ float red4[4][PIX];  // 1 KB
    __shared__ float invs[PIX];

    const int blk = blockIdx.x;
    const int b = blk >> 4;
    const int px0 = (blk & 15) * PIX;
    const int tid = threadIdx.x;
    const float* zb = z + (size_t)b * Cc * Nn + px0;  // zb[c*Nn + px]

    // ---------------- Phase A: per-pixel inverse norms ----------------
    {
        int px = tid & 63, q = tid >> 6;
        float ss = 0.f;
        for (int c = q; c < Cc; c += 4) {
            float v = zb[c * Nn + px];
            ss += v * v;
        }
        red4[q][px] = ss;
        __syncthreads();
        if (tid < PIX) {
            float t = red4[0][tid] + red4[1][tid] + red4[2][tid] + red4[3][tid];
            invs[tid] = 1.f / fmaxf(sqrtf(t), 1e-12f);
        }
        __syncthreads();
    }

    // ---------------- Phase B: scores GEMM (64px x 128m over C) ----------------
    const int tp = tid & 15;   // pixel group: px = tp*4 .. +3
    const int tm = tid >> 4;   // m group:     m  = tm*8 .. +7
    float acc[4][8];
#pragma unroll
    for (int i = 0; i < 4; ++i)
#pragma unroll
        for (int j = 0; j < 8; ++j) acc[i][j] = 0.f;

    for (int cb = 0; cb < Cc; cb += 32) {
        {   // stage z chunk: zs[cc][px]
            int r = tid >> 4;
            int px4 = (tid & 15) * 4;
            float4 v0 = *(const float4*)&zb[(cb + r) * Nn + px4];
            float4 v1 = *(const float4*)&zb[(cb + 16 + r) * Nn + px4];
            *(float4*)&zs[r][px4] = v0;
            *(float4*)&zs[16 + r][px4] = v1;
        }
        {   // stage memT chunk: ms[cc][m]
#pragma unroll
            for (int it = 0; it < 4; ++it) {
                int e = it * 256 + tid;
                int cc = e >> 5;
                int m4 = (e & 31) * 4;
                *(float4*)&ms[cc][m4] = *(const float4*)&memT[(cb + cc) * MP + m4];
            }
        }
        __syncthreads();
#pragma unroll 8
        for (int cc = 0; cc < 32; ++cc) {
            float4 zv = *(float4*)&zs[cc][tp * 4];
            float4 mv0 = *(float4*)&ms[cc][tm * 8];
            float4 mv1 = *(float4*)&ms[cc][tm * 8 + 4];
            float zz[4] = {zv.x, zv.y, zv.z, zv.w};
            float mw[8] = {mv0.x, mv0.y, mv0.z, mv0.w, mv1.x, mv1.y, mv1.z, mv1.w};
#pragma unroll
            for (int i = 0; i < 4; ++i)
#pragma unroll
                for (int j = 0; j < 8; ++j) acc[i][j] += zz[i] * mw[j];
        }
        __syncthreads();
    }
    // write scaled scores to scr
#pragma unroll
    for (int i = 0; i < 4; ++i) {
        float sc = invs[tp * 4 + i];
#pragma unroll
        for (int j = 0; j < 8; ++j) scr[tp * 4 + i][tm * 8 + j] = acc[i][j] * sc;
    }
    __syncthreads();

    // ---------------- Softmax + hard shrinkage (4 threads per pixel) ----------------
    {
        int px = tid & 63, q = tid >> 6;
        float ev[25];
        float mymax = -1e30f;
#pragma unroll
        for (int k = 0; k < 25; ++k) {
            float s = scr[px][q + 4 * k];
            ev[k] = s;
            mymax = fmaxf(mymax, s);
        }
        red4[q][px] = mymax;
        __syncthreads();
        float mx = fmaxf(fmaxf(red4[0][px], red4[1][px]), fmaxf(red4[2][px], red4[3][px]));
        float sum = 0.f;
#pragma unroll
        for (int k = 0; k < 25; ++k) {
            float e = expf(ev[k] - mx);
            ev[k] = e;
            sum += e;
        }
        __syncthreads();
        red4[q][px] = sum;
        __syncthreads();
        float tot = red4[0][px] + red4[1][px] + red4[2][px] + red4[3][px];
        float itot = 1.f / tot;
        float asum = 0.f;
#pragma unroll
        for (int k = 0; k < 25; ++k) {
            float w = ev[k] * itot;
            float d = w - 0.01f;
            float a = (d > 0.f) ? ((d * w) / (d + EPSF)) : 0.f;
            ev[k] = a;
            asum += a;
        }
        __syncthreads();
        red4[q][px] = asum;
        __syncthreads();
        float atot = red4[0][px] + red4[1][px] + red4[2][px] + red4[3][px] + EPSF;
        float ia = 1.f / atot;
        float* attnT = &scr[0][0];  // attnT[m*64 + px], 6400 floats <= scr
        size_t obase = ((size_t)(b * Nn + px0 + px)) * Mm;
#pragma unroll
        for (int k = 0; k < 25; ++k) {
            int m = q + 4 * k;
            float a = ev[k] * ia;
            attn_out[obase + m] = a;
            attnT[m * 64 + px] = a;
        }
    }
    __syncthreads();

    // ---------------- Phase C: z_hat = attn @ memory ----------------
    {
        const float* attnT = &scr[0][0];
        float(*msC)[MP] = ms;  // reuse: msC[20][128]
        const int tp2 = tid & 15;  // px group
        const int tc = tid >> 4;   // c group: c = cb + tc*8 .. +7
        for (int cb = 0; cb < Cc; cb += 128) {
            float acc2[4][8];
#pragma unroll
            for (int i = 0; i < 4; ++i)
#pragma unroll
                for (int j = 0; j < 8; ++j) acc2[i][j] = 0.f;

            for (int mb = 0; mb < Mm; mb += 20) {
                // stage mem rows chunk: msC[r][c] = mem[(mb+r)*Cc + cb + c], 20x128
#pragma unroll
                for (int it = 0; it < 3; ++it) {
                    int e = it * 256 + tid;
                    if (e < 640) {
                        int r = e >> 5;
                        int c4 = (e & 31) * 4;
                        *(float4*)&msC[r][c4] = *(const float4*)&mem[(size_t)(mb + r) * Cc + cb + c4];
                    }
                }
                __syncthreads();
#pragma unroll 4
                for (int m2 = 0; m2 < 20; ++m2) {
                    float4 av = *(const float4*)&attnT[(mb + m2) * 64 + tp2 * 4];
                    float4 m0 = *(const float4*)&msC[m2][tc * 8];
                    float4 m1 = *(const float4*)&msC[m2][tc * 8 + 4];
                    float aa[4] = {av.x, av.y, av.z, av.w};
                    float mw[8] = {m0.x, m0.y, m0.z, m0.w, m1.x, m1.y, m1.z, m1.w};
#pragma unroll
                    for (int i = 0; i < 4; ++i)
#pragma unroll
                        for (int j = 0; j < 8; ++j) acc2[i][j] += aa[i] * mw[j];
                }
                __syncthreads();
            }
            // store z_hat: [b][c][px0+px]
#pragma unroll
            for (int j = 0; j < 8; ++j) {
                int c = cb + tc * 8 + j;
                float4 v = make_float4(acc2[0][j], acc2[1][j], acc2[2][j], acc2[3][j]);
                *(float4*)&zhat[((size_t)b * Cc + c) * Nn + px0 + tp2 * 4] = v;
            }
        }
    }
}

extern "C" void kernel_launch(void* const* d_in, const int* in_sizes, int n_in,
                              void* d_out, int out_size, void* d_ws, size_t ws_size,
                              hipStream_t stream) {
    const float* z = (const float*)d_in[0];
    const float* mem = (const float*)d_in[1];
    float* out = (float*)d_out;
    float* zhat = out;                                   // 64*768*1024 floats
    float* attn = out + (size_t)Bn * Cc * Nn;            // 64*1024*100 floats
    float* memT = (float*)d_ws;                          // 768*128 floats = 393 KB

    prep_memT<<<MP, 256, 0, stream>>>(mem, memT);
    fused_mem_kernel<<<Bn * (Nn / PIX), 256, 0, stream>>>(z, mem, memT, zhat, attn);
}

// Round 3
// 237.662 us; speedup vs baseline: 2.0753x; 2.0753x over previous
//
#include <hip/hip_runtime.h>

#define EPSF 1e-8f

typedef __fp16   h2v   __attribute__((ext_vector_type(2)));
typedef _Float16 half8 __attribute__((ext_vector_type(8)));
typedef float    f32x16 __attribute__((ext_vector_type(16)));

constexpr int Bn = 64, Cc = 768, Nn = 1024, Mm = 100, MP = 128;

__device__ inline f32x16 zero16() {
    f32x16 z;
#pragma unroll
    for (int i = 0; i < 16; ++i) z[i] = 0.f;
    return z;
}

union U4H8 { uint4 u; half8 h; h2v p[4]; };

// Prep: normalized memory as f16 hi/lo [128][768] (rows >=100 zero), and
// unnormalized transposed memU f16 [768][128] (cols >=100 zero).
__global__ __launch_bounds__(256) void prep_kernel(const float* __restrict__ mem,
                                                   _Float16* __restrict__ mhi,
                                                   _Float16* __restrict__ mlo,
                                                   _Float16* __restrict__ mu) {
    int m = blockIdx.x, t = threadIdx.x;
    if (m >= Mm) {
        for (int c = t; c < Cc; c += 256) {
            mhi[m * Cc + c] = (_Float16)0.f;
            mlo[m * Cc + c] = (_Float16)0.f;
            mu[c * MP + m] = (_Float16)0.f;
        }
        return;
    }
    float ss = 0.f;
    for (int c = t; c < Cc; c += 256) { float v = mem[m * Cc + c]; ss += v * v; }
    __shared__ float red[256];
    red[t] = ss; __syncthreads();
    for (int s = 128; s > 0; s >>= 1) { if (t < s) red[t] += red[t + s]; __syncthreads(); }
    float inv = 1.f / fmaxf(sqrtf(red[0]), 1e-12f);
    for (int c = t; c < Cc; c += 256) {
        float v = mem[m * Cc + c], nv = v * inv;
        _Float16 h = (_Float16)nv;
        mhi[m * Cc + c] = h;
        mlo[m * Cc + c] = (_Float16)(nv - (float)h);
        mu[c * MP + m] = (_Float16)v;
    }
}

__global__ __launch_bounds__(256, 4) void fused_mem_kernel(
    const float* __restrict__ z, const _Float16* __restrict__ mhi,
    const _Float16* __restrict__ mlo, const _Float16* __restrict__ mu,
    float* __restrict__ zhat, float* __restrict__ attn_out) {
    // 33792 B LDS: zT hi/lo (32 KB, aliased later by scr fp32[64][128]) + red4
    __shared__ float smem[8448];
    _Float16* zhi = (_Float16*)smem;          // halves [64][128], 16B-block swizzled
    _Float16* zlo = (_Float16*)(smem + 4096);
    float* scr = smem;                        // fp32 [64][128], 16B-block swizzled
    float* red4 = smem + 8192;                // [4][64]

    const int blk = blockIdx.x;
    const int b = blk >> 4;
    const int px0 = (blk & 15) * 64;
    const int tid = threadIdx.x;
    const int w = tid >> 6;        // wave id
    const int l = tid & 63;        // lane
    const int pxl = l & 31;
    const int h = l >> 5;
    const int P0 = 32 * (w & 1);   // px-tile base (GEMM1 & GEMM2)
    const int M0 = 64 * (w >> 1);  // m-tile-pair base (GEMM1)
    const float* zb = z + (size_t)b * Cc * Nn + px0;  // zb[c*Nn + px]

    f32x16 acc0 = zero16(), acc1 = zero16();
    float ss = 0.f;
    const int pxs = l;  // staging px = lane (0..63)

    for (int ch = 0; ch < 6; ++ch) {
        __syncthreads();  // previous chunk's MFMA reads done before overwrite
        // ---- stage: global [128c][64px] fp32 -> transposed f16 hi/lo LDS ----
#pragma unroll
        for (int i = 0; i < 4; ++i) {
            int cl0 = (i * 4 + w) * 8;  // c within chunk, 8 consecutive
            const float* src = zb + (size_t)(ch * 128 + cl0) * Nn + pxs;
            float v0 = src[0 * Nn], v1 = src[1 * Nn], v2 = src[2 * Nn], v3 = src[3 * Nn];
            float v4 = src[4 * Nn], v5 = src[5 * Nn], v6 = src[6 * Nn], v7 = src[7 * Nn];
            ss += v0 * v0 + v1 * v1 + v2 * v2 + v3 * v3 + v4 * v4 + v5 * v5 + v6 * v6 + v7 * v7;
            U4H8 hi, lo;
            h2v p;
            p = __builtin_amdgcn_cvt_pkrtz(v0, v1); hi.p[0] = p;
            lo.p[0] = __builtin_amdgcn_cvt_pkrtz(v0 - (float)p.x, v1 - (float)p.y);
            p = __builtin_amdgcn_cvt_pkrtz(v2, v3); hi.p[1] = p;
            lo.p[1] = __builtin_amdgcn_cvt_pkrtz(v2 - (float)p.x, v3 - (float)p.y);
            p = __builtin_amdgcn_cvt_pkrtz(v4, v5); hi.p[2] = p;
            lo.p[2] = __builtin_amdgcn_cvt_pkrtz(v4 - (float)p.x, v5 - (float)p.y);
            p = __builtin_amdgcn_cvt_pkrtz(v6, v7); hi.p[3] = p;
            lo.p[3] = __builtin_amdgcn_cvt_pkrtz(v6 - (float)p.x, v7 - (float)p.y);
            int bswz = ((cl0 >> 3) ^ (pxs & 15)) * 8;
            *(uint4*)&zhi[pxs * 128 + bswz] = hi.u;
            *(uint4*)&zlo[pxs * 128 + bswz] = lo.u;
        }
        __syncthreads();
        // ---- GEMM1: 8 K-steps of 16 over this chunk ----
#pragma unroll 2
        for (int cs = 0; cs < 8; ++cs) {
            int cg = ch * 128 + cs * 16 + h * 8;  // global c for this lane's 8 elems
            int bswz = ((cs * 2 + h) ^ (pxl & 15)) * 8;
            U4H8 A;
            A.u = *(const uint4*)&zhi[(P0 + pxl) * 128 + bswz];
            half8 ahi = A.h;
            A.u = *(const uint4*)&zlo[(P0 + pxl) * 128 + bswz];
            half8 alo = A.h;
            const _Float16* bp = mhi + (size_t)(M0 + pxl) * Cc + cg;
            const _Float16* bq = mlo + (size_t)(M0 + pxl) * Cc + cg;
            U4H8 B0h, B0l, B1h, B1l;
            B0h.u = *(const uint4*)bp;
            B1h.u = *(const uint4*)(bp + 32 * Cc);
            B0l.u = *(const uint4*)bq;
            B1l.u = *(const uint4*)(bq + 32 * Cc);
            acc0 = __builtin_amdgcn_mfma_f32_32x32x16_f16(ahi, B0h.h, acc0, 0, 0, 0);
            acc0 = __builtin_amdgcn_mfma_f32_32x32x16_f16(ahi, B0l.h, acc0, 0, 0, 0);
            acc0 = __builtin_amdgcn_mfma_f32_32x32x16_f16(alo, B0h.h, acc0, 0, 0, 0);
            acc1 = __builtin_amdgcn_mfma_f32_32x32x16_f16(ahi, B1h.h, acc1, 0, 0, 0);
            acc1 = __builtin_amdgcn_mfma_f32_32x32x16_f16(ahi, B1l.h, acc1, 0, 0, 0);
            acc1 = __builtin_amdgcn_mfma_f32_32x32x16_f16(alo, B1h.h, acc1, 0, 0, 0);
        }
    }
    __syncthreads();  // last MFMA reads done; zT region becomes scr

    // ---- epilogue: raw scores -> swizzled scr; z-norm partials -> red4 ----
    red4[w * 64 + l] = ss;
#pragma unroll
    for (int r = 0; r < 16; ++r) {
        int pxr = P0 + (r & 3) + 8 * (r >> 2) + 4 * h;
        int sw = pxr & 31;
        int m0a = M0 + pxl;
        scr[pxr * 128 + ((((m0a >> 2) ^ sw) << 2) | (m0a & 3))] = acc0[r];
        int m1a = M0 + 32 + pxl;
        scr[pxr * 128 + ((((m1a >> 2) ^ sw) << 2) | (m1a & 3))] = acc1[r];
    }
    __syncthreads();

    // ---- softmax + hard shrinkage (thread: px = lane, q = wave) ----
    {
        int px = l, q = w;
        float nrm2 = red4[px] + red4[64 + px] + red4[128 + px] + red4[192 + px];
        float invn = 1.f / fmaxf(sqrtf(nrm2), 1e-12f);
        __syncthreads();
        int swb = px & 31;
        float ev[25];
        float mymax = -1e30f;
#pragma unroll
        for (int k = 0; k < 25; ++k) {
            float s = scr[px * 128 + (((k ^ swb) << 2) | q)] * invn;
            ev[k] = s;
            mymax = fmaxf(mymax, s);
        }
        red4[q * 64 + px] = mymax; __syncthreads();
        float mx = fmaxf(fmaxf(red4[px], red4[64 + px]), fmaxf(red4[128 + px], red4[192 + px]));
        float sum = 0.f;
#pragma unroll
        for (int k = 0; k < 25; ++k) { float e = expf(ev[k] - mx); ev[k] = e; sum += e; }
        __syncthreads();
        red4[q * 64 + px] = sum; __syncthreads();
        float tot = red4[px] + red4[64 + px] + red4[128 + px] + red4[192 + px];
        float itot = 1.f / tot, asum = 0.f;
#pragma unroll
        for (int k = 0; k < 25; ++k) {
            float wgt = ev[k] * itot, d = wgt - 0.01f;
            float a = (d > 0.f) ? (d * wgt) / (d + EPSF) : 0.f;
            ev[k] = a; asum += a;
        }
        __syncthreads();
        red4[q * 64 + px] = asum; __syncthreads();
        float atot = red4[px] + red4[64 + px] + red4[128 + px] + red4[192 + px] + EPSF;
        float ia = 1.f / atot;
        size_t obase = ((size_t)(b * Nn + px0 + px)) * (size_t)Mm;
#pragma unroll
        for (int k = 0; k < 25; ++k) {
            float a = ev[k] * ia;
            attn_out[obase + q + 4 * k] = a;
            scr[px * 128 + (((k ^ swb) << 2) | q)] = a;
        }
        // zero pad m = 100..127 for GEMM2's K loop
        for (int k2 = 25 + q; k2 < 32; k2 += 4) {
            int cb = (k2 ^ swb) << 2;
            scr[px * 128 + cb] = 0.f; scr[px * 128 + cb + 1] = 0.f;
            scr[px * 128 + cb + 2] = 0.f; scr[px * 128 + cb + 3] = 0.f;
        }
    }
    __syncthreads();

    // ---- GEMM2: z_hat = attn @ memory (A = memU f16 from L2, B = attn from scr) ----
    {
        const int CH = (w >> 1) * 384;  // this wave's 384-channel half
        float* zo = zhat + (size_t)b * Cc * Nn + px0 + P0 + pxl;
        const int row = P0 + pxl;
#pragma unroll 1
        for (int g = 0; g < 3; ++g) {
            int Cbase = CH + g * 128;
            f32x16 a0 = zero16(), a1 = zero16(), a2 = zero16(), a3 = zero16();
#pragma unroll 2
            for (int ms = 0; ms < 8; ++ms) {
                int m0 = ms * 16 + h * 8;
                float4 fa = *(const float4*)&scr[row * 128 + ((((m0 >> 2)) ^ pxl) << 2)];
                float4 fb = *(const float4*)&scr[row * 128 + ((((m0 >> 2) + 1) ^ pxl) << 2)];
                U4H8 bs;
                bs.p[0] = __builtin_amdgcn_cvt_pkrtz(fa.x, fa.y);
                bs.p[1] = __builtin_amdgcn_cvt_pkrtz(fa.z, fa.w);
                bs.p[2] = __builtin_amdgcn_cvt_pkrtz(fb.x, fb.y);
                bs.p[3] = __builtin_amdgcn_cvt_pkrtz(fb.z, fb.w);
                const _Float16* ap = mu + (size_t)(Cbase + pxl) * MP + m0;
                U4H8 A0, A1, A2, A3;
                A0.u = *(const uint4*)(ap);
                A1.u = *(const uint4*)(ap + 32 * MP);
                A2.u = *(const uint4*)(ap + 64 * MP);
                A3.u = *(const uint4*)(ap + 96 * MP);
                a0 = __builtin_amdgcn_mfma_f32_32x32x16_f16(A0.h, bs.h, a0, 0, 0, 0);
                a1 = __builtin_amdgcn_mfma_f32_32x32x16_f16(A1.h, bs.h, a1, 0, 0, 0);
                a2 = __builtin_amdgcn_mfma_f32_32x32x16_f16(A2.h, bs.h, a2, 0, 0, 0);
                a3 = __builtin_amdgcn_mfma_f32_32x32x16_f16(A3.h, bs.h, a3, 0, 0, 0);
            }
#pragma unroll
            for (int r = 0; r < 16; ++r) {
                int cl = (r & 3) + 8 * (r >> 2) + 4 * h;
                zo[(size_t)(Cbase + cl) * Nn] = a0[r];
                zo[(size_t)(Cbase + 32 + cl) * Nn] = a1[r];
                zo[(size_t)(Cbase + 64 + cl) * Nn] = a2[r];
                zo[(size_t)(Cbase + 96 + cl) * Nn] = a3[r];
            }
        }
    }
}

extern "C" void kernel_launch(void* const* d_in, const int* in_sizes, int n_in,
                              void* d_out, int out_size, void* d_ws, size_t ws_size,
                              hipStream_t stream) {
    const float* z = (const float*)d_in[0];
    const float* mem = (const float*)d_in[1];
    float* out = (float*)d_out;
    float* zhat = out;                         // 64*768*1024
    float* attn = out + (size_t)Bn * Cc * Nn;  // 64*1024*100
    _Float16* mhi = (_Float16*)d_ws;           // [128][768]
    _Float16* mlo = mhi + MP * Cc;             // [128][768]
    _Float16* mu = mlo + MP * Cc;              // [768][128]

    prep_kernel<<<MP, 256, 0, stream>>>(mem, mhi, mlo, mu);
    fused_mem_kernel<<<Bn * 16, 256, 0, stream>>>(z, mhi, mlo, mu, zhat, attn);
}

// Round 4
// 143.284 us; speedup vs baseline: 3.4423x; 1.6587x over previous
//
#include <hip/hip_runtime.h>

#define EPSF 1e-8f

typedef __fp16   h2v   __attribute__((ext_vector_type(2)));
typedef _Float16 half8 __attribute__((ext_vector_type(8)));
typedef float    f32x16 __attribute__((ext_vector_type(16)));

constexpr int Bn = 64, Cc = 768, Nn = 1024, Mm = 100;

__device__ inline f32x16 zero16() {
    f32x16 z;
#pragma unroll
    for (int i = 0; i < 16; ++i) z[i] = 0.f;
    return z;
}

union U4H8 { uint4 u; half8 h; h2v p[4]; };

__device__ inline unsigned pkr(float a, float b) {
    union { h2v p; unsigned u; } cv;
    cv.p = __builtin_amdgcn_cvt_pkrtz(a, b);
    return cv.u;
}

// Fragment-major prep.
// GEMM1 A (normalized mem, hi/lo f16):  idx = ((cs*4 + mt)*64 + hb*32 + ml)*8 + j
//   where cs=c>>4, hb=(c>>3)&1, j=c&7, mt=m>>5, ml=m&31.   [48*4*64*8 f16 = 192KB]
// GEMM2 A (raw mem, transposed):        idx = ((ct*8 + ms)*64 + hm*32 + cl)*8 + jm
//   where ct=c>>5, cl=c&31, ms=m>>4, hm=(m>>3)&1, jm=m&7.  [24*8*64*8 f16 = 192KB]
__global__ __launch_bounds__(256) void prep_kernel(const float* __restrict__ mem,
                                                   _Float16* __restrict__ mhiF,
                                                   _Float16* __restrict__ mloF,
                                                   _Float16* __restrict__ muF) {
    int m = blockIdx.x, t = threadIdx.x;
    float inv = 0.f;
    if (m < Mm) {
        float ss = 0.f;
        for (int c = t; c < Cc; c += 256) { float v = mem[m * Cc + c]; ss += v * v; }
        __shared__ float red[256];
        red[t] = ss; __syncthreads();
        for (int s = 128; s > 0; s >>= 1) { if (t < s) red[t] += red[t + s]; __syncthreads(); }
        inv = 1.f / fmaxf(sqrtf(red[0]), 1e-12f);
    }
    for (int c = t; c < Cc; c += 256) {
        float v = (m < Mm) ? mem[m * Cc + c] : 0.f;
        float nv = v * inv;
        _Float16 hh = (_Float16)nv;
        _Float16 ll = (_Float16)(nv - (float)hh);
        int cs = c >> 4, hb = (c >> 3) & 1, j = c & 7, mt = m >> 5, ml = m & 31;
        size_t idx = ((size_t)(cs * 4 + mt) * 64 + hb * 32 + ml) * 8 + j;
        mhiF[idx] = hh;
        mloF[idx] = ll;
        int ct = c >> 5, cl = c & 31, ms = m >> 4, hm = (m >> 3) & 1, jm = m & 7;
        size_t idx2 = ((size_t)(ct * 8 + ms) * 64 + hm * 32 + cl) * 8 + jm;
        muF[idx2] = (_Float16)v;
    }
}

// One independent wave per 32 pixels. No LDS, no barriers.
__global__ __launch_bounds__(256, 2) void fused_mem_kernel(
    const float* __restrict__ z, const _Float16* __restrict__ mhiF,
    const _Float16* __restrict__ mloF, const _Float16* __restrict__ muF,
    float* __restrict__ zhat, float* __restrict__ attn_out) {
    const int tid = threadIdx.x;
    const int l = tid & 63;
    const int wid = (blockIdx.x << 2) | (tid >> 6);  // 0..2047
    const int b = wid >> 5;
    const int pxb = (wid & 31) * 32;  // base px within image
    const int pl = l & 31;            // lane's px / col
    const int h = l >> 5;             // k-half
    const float* zp = z + (size_t)b * Cc * Nn + pxb + pl;

    // ---------------- GEMM1: scoresT[m][px] = mem_norm . z ----------------
    f32x16 acc[4] = {zero16(), zero16(), zero16(), zero16()};
    float ss = 0.f;
    const float* zr = zp + (size_t)h * 8 * Nn;
    const uint4* mh4 = (const uint4*)mhiF;
    const uint4* ml4 = (const uint4*)mloF;

    float zc[8], zn[8];
    uint4 fh[4], fl_[4], fh2[4], fl2[4];
#pragma unroll
    for (int j = 0; j < 8; ++j) zc[j] = zr[(size_t)j * Nn];
#pragma unroll
    for (int mt = 0; mt < 4; ++mt) { fh[mt] = mh4[mt * 64 + l]; fl_[mt] = ml4[mt * 64 + l]; }

#pragma unroll 2
    for (int cs = 0; cs < 48; ++cs) {
        if (cs < 47) {  // prefetch next K-step
#pragma unroll
            for (int j = 0; j < 8; ++j) zn[j] = zr[(size_t)((cs + 1) * 16 + j) * Nn];
#pragma unroll
            for (int mt = 0; mt < 4; ++mt) {
                fh2[mt] = mh4[((cs + 1) * 4 + mt) * 64 + l];
                fl2[mt] = ml4[((cs + 1) * 4 + mt) * 64 + l];
            }
        }
        // convert current z to f16 hi/lo, accumulate norm
        U4H8 zh, zl8;
#pragma unroll
        for (int t = 0; t < 4; ++t) {
            float u = zc[2 * t], v = zc[2 * t + 1];
            h2v p = __builtin_amdgcn_cvt_pkrtz(u, v);
            zh.p[t] = p;
            zl8.p[t] = __builtin_amdgcn_cvt_pkrtz(u - (float)p.x, v - (float)p.y);
            ss += u * u + v * v;
        }
#pragma unroll
        for (int mt = 0; mt < 4; ++mt) {
            U4H8 ah, al;
            ah.u = fh[mt]; al.u = fl_[mt];
            acc[mt] = __builtin_amdgcn_mfma_f32_32x32x16_f16(ah.h, zh.h, acc[mt], 0, 0, 0);
            acc[mt] = __builtin_amdgcn_mfma_f32_32x32x16_f16(al.h, zh.h, acc[mt], 0, 0, 0);
            acc[mt] = __builtin_amdgcn_mfma_f32_32x32x16_f16(ah.h, zl8.h, acc[mt], 0, 0, 0);
        }
#pragma unroll
        for (int j = 0; j < 8; ++j) zc[j] = zn[j];
#pragma unroll
        for (int mt = 0; mt < 4; ++mt) { fh[mt] = fh2[mt]; fl_[mt] = fl2[mt]; }
    }

    // ---------------- in-register softmax + hard shrinkage ----------------
    // lane (pl, h) holds scores for px = pxb+pl at m = mt*32 + (rr&3)+8*(rr>>2)+4h
    ss += __shfl_xor(ss, 32);
    float invn = 1.f / fmaxf(sqrtf(ss), 1e-12f);

    float a_[64];
#pragma unroll
    for (int r = 0; r < 64; ++r) {
        int mt = r >> 4, rr = r & 15;
        float v = acc[mt][rr] * invn;
        if (r >= 52) v = -3.0e38f;
        else if (r >= 48) v = (h == 0) ? v : -3.0e38f;  // tile3: only m=96..99 valid
        a_[r] = v;
    }
    float mx = -3.0e38f;
#pragma unroll
    for (int r = 0; r < 52; ++r) mx = fmaxf(mx, a_[r]);
    mx = fmaxf(mx, __shfl_xor(mx, 32));

    float sum = 0.f;
#pragma unroll
    for (int r = 0; r < 52; ++r) { float e = expf(a_[r] - mx); a_[r] = e; sum += e; }
    sum += __shfl_xor(sum, 32);
    float itot = 1.f / sum;

    float asum = 0.f;
#pragma unroll
    for (int r = 0; r < 52; ++r) {
        float w = a_[r] * itot;
        float d = w - 0.01f;
        float aa = (d > 0.f) ? (d * w) / (d + EPSF) : 0.f;
        a_[r] = aa; asum += aa;
    }
    asum += __shfl_xor(asum, 32);
    float ia = 1.f / (asum + EPSF);
#pragma unroll
    for (int r = 0; r < 52; ++r) a_[r] *= ia;
#pragma unroll
    for (int r = 52; r < 64; ++r) a_[r] = 0.f;

    // ---- store attn (float4 groups; group g covers m0..m0+3) ----
    {
        size_t ob = (size_t)(wid * 32 + pl) * (size_t)Mm;
#pragma unroll
        for (int g = 0; g < 13; ++g) {
            int r0 = g * 4;
            int m0 = (r0 >> 4) * 32 + 8 * ((r0 >> 2) & 3) + 4 * h;
            if (g < 12 || h == 0) {
                float4 v = make_float4(a_[r0], a_[r0 + 1], a_[r0 + 2], a_[r0 + 3]);
                *(float4*)&attn_out[ob + m0] = v;
            }
        }
    }

    // ---- build GEMM2 B-fragments (attn as f16, k=m layout) in-register ----
    uint4 bfr[8];
#pragma unroll
    for (int mt = 0; mt < 4; ++mt) {
        unsigned p0 = pkr(a_[16 * mt + 0], a_[16 * mt + 1]);
        unsigned p1 = pkr(a_[16 * mt + 2], a_[16 * mt + 3]);
        unsigned p2 = pkr(a_[16 * mt + 4], a_[16 * mt + 5]);
        unsigned p3 = pkr(a_[16 * mt + 6], a_[16 * mt + 7]);
        unsigned p4 = pkr(a_[16 * mt + 8], a_[16 * mt + 9]);
        unsigned p5 = pkr(a_[16 * mt + 10], a_[16 * mt + 11]);
        unsigned p6 = pkr(a_[16 * mt + 12], a_[16 * mt + 13]);
        unsigned p7 = pkr(a_[16 * mt + 14], a_[16 * mt + 15]);
        unsigned s0 = __shfl_xor(p0, 32), s1 = __shfl_xor(p1, 32);
        unsigned s2 = __shfl_xor(p2, 32), s3 = __shfl_xor(p3, 32);
        unsigned s4 = __shfl_xor(p4, 32), s5 = __shfl_xor(p5, 32);
        unsigned s6 = __shfl_xor(p6, 32), s7 = __shfl_xor(p7, 32);
        bfr[2 * mt]     = h ? make_uint4(s2, s3, p2, p3) : make_uint4(p0, p1, s0, s1);
        bfr[2 * mt + 1] = h ? make_uint4(s6, s7, p6, p7) : make_uint4(p4, p5, s4, s5);
    }

    // ---------------- GEMM2: z_hat[c][px] = memT . attn ----------------
    const uint4* mu4 = (const uint4*)muF;
    float* zo = zhat + (size_t)b * Cc * Nn + pxb + pl;
#pragma unroll 1
    for (int ct = 0; ct < 24; ct += 2) {
        f32x16 a2 = zero16(), a3 = zero16();
#pragma unroll
        for (int ms = 0; ms < 8; ++ms) {
            U4H8 A0, A1, Bf;
            A0.u = mu4[(ct * 8 + ms) * 64 + l];
            A1.u = mu4[((ct + 1) * 8 + ms) * 64 + l];
            Bf.u = bfr[ms];
            a2 = __builtin_amdgcn_mfma_f32_32x32x16_f16(A0.h, Bf.h, a2, 0, 0, 0);
            a3 = __builtin_amdgcn_mfma_f32_32x32x16_f16(A1.h, Bf.h, a3, 0, 0, 0);
        }
#pragma unroll
        for (int r = 0; r < 16; ++r) {
            int cl = (r & 3) + 8 * (r >> 2) + 4 * h;
            zo[(size_t)(ct * 32 + cl) * Nn] = a2[r];
            zo[(size_t)(ct * 32 + 32 + cl) * Nn] = a3[r];
        }
    }
}

extern "C" void kernel_launch(void* const* d_in, const int* in_sizes, int n_in,
                              void* d_out, int out_size, void* d_ws, size_t ws_size,
                              hipStream_t stream) {
    const float* z = (const float*)d_in[0];
    const float* mem = (const float*)d_in[1];
    float* out = (float*)d_out;
    float* zhat = out;                          // 64*768*1024
    float* attn = out + (size_t)Bn * Cc * Nn;   // 64*1024*100
    _Float16* mhiF = (_Float16*)d_ws;           // 192 KB
    _Float16* mloF = mhiF + 48 * 4 * 64 * 8;    // 192 KB
    _Float16* muF = mloF + 48 * 4 * 64 * 8;     // 192 KB

    prep_kernel<<<128, 256, 0, stream>>>(mem, mhiF, mloF, muF);
    fused_mem_kernel<<<512, 256, 0, stream>>>(z, mhiF, mloF, muF, zhat, attn);
}